// Round 19
// baseline (47.922 us; speedup 1.0000x reference)
//
#include <hip/hip_runtime.h>

#define NDIM 4096
#define LDIM 128
#define EDIM 12
#define HDIM 32
#define XPITCH 24   // u16 pitch for staged x rows (16 used; 48B, b128-aligned)

typedef float    f4v __attribute__((ext_vector_type(4)));
typedef _Float16 h2  __attribute__((ext_vector_type(2)));
typedef _Float16 h4  __attribute__((ext_vector_type(4)));

#ifndef __has_builtin
#define __has_builtin(x) 0
#endif

__device__ __forceinline__ float ex2_(float v) {
#if __has_builtin(__builtin_amdgcn_exp2f)
    return __builtin_amdgcn_exp2f(v);
#else
    return exp2f(v);
#endif
}
__device__ __forceinline__ float rcp_(float v) {
#if __has_builtin(__builtin_amdgcn_rcpf)
    return __builtin_amdgcn_rcpf(v);
#else
    return 1.0f / v;
#endif
}
__device__ __forceinline__ float rsq_(float v) {
#if __has_builtin(__builtin_amdgcn_rsqf)
    return __builtin_amdgcn_rsqf(v);
#else
    return rsqrtf(v);
#endif
}
// tanh(v) = 1 - 2/(e^{2v}+1)
__device__ __forceinline__ float tanh_(float v) {
    float t = ex2_(v * 2.8853900817779268f);
    return 1.0f - 2.0f * rcp_(t + 1.0f);
}

__device__ __forceinline__ h2 pk16(float a, float b) {
#if __has_builtin(__builtin_amdgcn_cvt_pkrtz)
    return __builtin_bit_cast(h2, __builtin_amdgcn_cvt_pkrtz(a, b));
#else
    h2 r; r.x = (_Float16)a; r.y = (_Float16)b; return r;
#endif
}
__device__ __forceinline__ unsigned int h2u(h2 a) { return __builtin_bit_cast(unsigned int, a); }
__device__ __forceinline__ h4 mkh4(h2 a, h2 b) {
    h4 r; r.x = a.x; r.y = a.y; r.z = b.x; r.w = b.y; return r;
}
__device__ __forceinline__ h4 cvt_h4(float4 w) { return mkh4(pk16(w.x, w.y), pk16(w.z, w.w)); }
__device__ __forceinline__ h4 h4z() {
    h4 r; r.x = (_Float16)0; r.y = (_Float16)0; r.z = (_Float16)0; r.w = (_Float16)0; return r;
}

__device__ __forceinline__ f4v mfma16(h4 a, h4 b, f4v c) {
    return __builtin_amdgcn_mfma_f32_16x16x16f16(a, b, c, 0, 0, 0);
}

__global__ __launch_bounds__(512)
void encoder_fused(const float* __restrict__ x,
                   const float* __restrict__ inw, const float* __restrict__ inb,
                   const float* __restrict__ ow,  const float* __restrict__ ob,
                   const float* __restrict__ w1,  const float* __restrict__ b1,
                   const float* __restrict__ w2,  const float* __restrict__ b2,
                   const float* __restrict__ w3,  const float* __restrict__ b3,
                   const float* __restrict__ g1,  const float* __restrict__ be1,
                   const float* __restrict__ g2,  const float* __restrict__ be2,
                   float* __restrict__ out)
{
    const int tid  = threadIdx.x;
    const int w    = tid >> 6;         // wave 0..7
    const int p    = w >> 2;           // n within block (0..1)
    const int wq   = w & 3;            // quarter: samples 32*wq..+31
    const int lane = tid & 63;
    const int fr   = lane & 15;        // fragment row/col slot
    const int fg   = lane >> 4;        // fragment k-group (0..3)
    const int n    = blockIdx.x * 2 + p;
    const bool e_ok = (fg < 3);        // feat 4*fg+j < 12

    __shared__ unsigned short sXh[2][LDIM][XPITCH];  // x rows f16
    __shared__ unsigned short sVT[2][13][132];       // V^T f16 + ones row 12
    __shared__ h4             sKf[2][8][64];         // K A-frags per key tile

    const float SCALE = 0.2886751345948129f;   // 1/sqrt(12)
    const float L2E   = 1.4426950408889634f;
    const float SL2E  = SCALE * L2E;
    const f4v   FZ    = (f4v){0.f, 0.f, 0.f, 0.f};

    // ================= stage x rows as f16 (first 256 threads) =============
    if (tid < 256) {
        const int ps = tid >> 7, ls = tid & 127;
        const int ns = blockIdx.x * 2 + ps;
        const float* xp = x + ((size_t)ls * NDIM + ns) * EDIM;
        float4 xa = *reinterpret_cast<const float4*>(xp);
        float4 xb = *reinterpret_cast<const float4*>(xp + 4);
        float4 xc = *reinterpret_cast<const float4*>(xp + 8);
        unsigned int u0 = h2u(pk16(xa.x, xa.y)), u1 = h2u(pk16(xa.z, xa.w));
        unsigned int u2 = h2u(pk16(xb.x, xb.y)), u3 = h2u(pk16(xb.z, xb.w));
        unsigned int u4 = h2u(pk16(xc.x, xc.y)), u5 = h2u(pk16(xc.z, xc.w));
        *reinterpret_cast<uint4*>(&sXh[ps][ls][0]) = make_uint4(u0, u1, u2, u3);
        *reinterpret_cast<uint4*>(&sXh[ps][ls][8]) = make_uint4(u4, u5, 0u, 0u);
        // ones row for the psum-via-MFMA trick (V^T feature row 12)
        sVT[ps][12][ls] = (unsigned short)0x3C00;   // f16 1.0
    }

    // ---- projection weight A-frags (rows fr = fout, k = feat 4fg+j) ----
    h4 WQp = h4z(), WKp = h4z(), WVp = h4z();
    if (fr < 12 && e_ok) {
        WQp = cvt_h4(*reinterpret_cast<const float4*>(inw + (     fr) * 12 + 4 * fg));
        WKp = cvt_h4(*reinterpret_cast<const float4*>(inw + (12 + fr) * 12 + 4 * fg));
        WVp = cvt_h4(*reinterpret_cast<const float4*>(inw + (24 + fr) * 12 + 4 * fg));
    }
    const float4 F4Z = make_float4(0.f, 0.f, 0.f, 0.f);
    float4 bq4 = e_ok ? *reinterpret_cast<const float4*>(inb +      4 * fg) : F4Z;
    float4 bk4 = e_ok ? *reinterpret_cast<const float4*>(inb + 12 + 4 * fg) : F4Z;
    float4 bv4 = e_ok ? *reinterpret_cast<const float4*>(inb + 24 + 4 * fg) : F4Z;
    // fold SCALE*L2E into the Q bias (softmax shift deleted: per-query uniform
    // scaling of p cancels between O and the ones-row denominator)
    float4 bq4s = make_float4(bq4.x * SL2E, bq4.y * SL2E, bq4.z * SL2E, bq4.w * SL2E);

    __syncthreads();   // sXh fully staged before cross-wave MFMA reads

    // ================= phase 1: QKV projection via MFMA (2 tiles/wave) =====
    h4 qf[2];
    #pragma unroll
    for (int st = 0; st < 2; ++st) {
        const int srow = 32 * wq + 16 * st;    // base sample/key of this tile
        h4 xB = *reinterpret_cast<const h4*>(&sXh[p][srow + fr][4 * fg]);

        // Q: C-layout == B-frag for QK^T; q * SCALE * L2E in one fma each
        f4v Dq = mfma16(WQp, xB, FZ);
        qf[st] = mkh4(pk16(fmaf(Dq[0], SL2E, bq4s.x), fmaf(Dq[1], SL2E, bq4s.y)),
                      pk16(fmaf(Dq[2], SL2E, bq4s.z), fmaf(Dq[3], SL2E, bq4s.w)));

        // K: C-layout == A-frag for S^T; park in LDS for cross-wave reads
        f4v Dk = mfma16(WKp, xB, FZ);
        sKf[p][2 * wq + st][lane] = mkh4(pk16(Dk[0] + bk4.x, Dk[1] + bk4.y),
                                         pk16(Dk[2] + bk4.z, Dk[3] + bk4.w));

        // V: transpose into sVT[feat][key] for the PV A-frag
        f4v Dv = mfma16(WVp, xB, FZ);
        if (e_ok) {
            sVT[p][4*fg + 0][srow + fr] = __builtin_bit_cast(unsigned short, (_Float16)(Dv[0] + bv4.x));
            sVT[p][4*fg + 1][srow + fr] = __builtin_bit_cast(unsigned short, (_Float16)(Dv[1] + bv4.y));
            sVT[p][4*fg + 2][srow + fr] = __builtin_bit_cast(unsigned short, (_Float16)(Dv[2] + bv4.z));
            sVT[p][4*fg + 3][srow + fr] = __builtin_bit_cast(unsigned short, (_Float16)(Dv[3] + bv4.w));
        }
    }
    __syncthreads();   // sKf / sVT complete (written by all 4 waves of each n)

    // ================= phase 2: attention via MFMA (no softmax shift) ======
    f4v oc[2];
    oc[0] = FZ; oc[1] = FZ;

    #pragma unroll
    for (int u = 0; u < 8; ++u) {
        h4 kf = sKf[p][u][lane];
        h4 vf = h4z();
        if (fr <= 12)   // rows 0..11 = V features, row 12 = ones (psum row)
            vf = *reinterpret_cast<const h4*>(&sVT[p][fr][16 * u + 4 * fg]);
        #pragma unroll
        for (int st = 0; st < 2; ++st) {
            f4v c = mfma16(kf, qf[st], FZ);    // S^T[key][query] * log2(e)
            float p0 = ex2_(c[0]);
            float p1 = ex2_(c[1]);
            float p2 = ex2_(c[2]);
            float p3 = ex2_(c[3]);
            h4 paf = mkh4(pk16(p0, p1), pk16(p2, p3));
            oc[st] = mfma16(vf, paf, oc[st]);  // O^T[feat][sample]; row12 = psum
        }
    }
    float inv[2];
    #pragma unroll
    for (int st = 0; st < 2; ++st) {
        float ps = __shfl(oc[st][0], fr + 48);   // row 12 lives at (fr, fg=3), j=0
        inv[st] = rcp_(fmaxf(ps, 1e-35f));
    }

    // ============ epilogue constants: weight A-frags (f16) + biases ========
    h4 OWf = h4z();
    if (fr < 12 && e_ok)
        OWf = cvt_h4(*reinterpret_cast<const float4*>(ow + fr * 12 + 4 * fg));
    h4 W1f[2] = {h4z(), h4z()};
    if (e_ok) {
        W1f[0] = cvt_h4(*reinterpret_cast<const float4*>(w1 + (fr     ) * 12 + 4 * fg));
        W1f[1] = cvt_h4(*reinterpret_cast<const float4*>(w1 + (fr + 16) * 12 + 4 * fg));
    }
    h4 W2f[2][2];
    #pragma unroll
    for (int gt = 0; gt < 2; ++gt)
        #pragma unroll
        for (int ks = 0; ks < 2; ++ks)
            W2f[gt][ks] = cvt_h4(*reinterpret_cast<const float4*>(
                w2 + (16*gt + fr) * 32 + 16*ks + 4*fg));
    h4 W3f[2] = {h4z(), h4z()};
    if (fr < 12) {
        W3f[0] = cvt_h4(*reinterpret_cast<const float4*>(w3 + fr * 32 +      4 * fg));
        W3f[1] = cvt_h4(*reinterpret_cast<const float4*>(w3 + fr * 32 + 16 + 4 * fg));
    }
    float4 ob4  = e_ok ? *reinterpret_cast<const float4*>(ob  + 4*fg) : F4Z;
    float4 b3v  = e_ok ? *reinterpret_cast<const float4*>(b3  + 4*fg) : F4Z;
    float4 g1v  = e_ok ? *reinterpret_cast<const float4*>(g1  + 4*fg) : F4Z;
    float4 be1v = e_ok ? *reinterpret_cast<const float4*>(be1 + 4*fg) : F4Z;
    float4 g2v  = e_ok ? *reinterpret_cast<const float4*>(g2  + 4*fg) : F4Z;
    float4 be2v = e_ok ? *reinterpret_cast<const float4*>(be2 + 4*fg) : F4Z;
    float4 b1t0 = *reinterpret_cast<const float4*>(b1 +      4*fg);
    float4 b1t1 = *reinterpret_cast<const float4*>(b1 + 16 + 4*fg);
    float4 b2t0 = *reinterpret_cast<const float4*>(b2 +      4*fg);
    float4 b2t1 = *reinterpret_cast<const float4*>(b2 + 16 + 4*fg);

    // ================= phase 3: fused MFMA epilogue (2 tiles/wave) =========
    #pragma unroll
    for (int st = 0; st < 2; ++st) {
        const int sample = 32*wq + 16*st + fr;
        // normalized O^T as B-frag (f16)
        h4 B0 = mkh4(pk16(oc[st][0]*inv[st], oc[st][1]*inv[st]),
                     pk16(oc[st][2]*inv[st], oc[st][3]*inv[st]));
        // out-proj: D0 = OW . O -> AttnProj^T[fout][sample]
        f4v D0 = mfma16(OWf, B0, FZ);
        float r0 = 0.f, r1 = 0.f, r2_ = 0.f, r3 = 0.f;
        if (e_ok) {
            h4 xh4 = *reinterpret_cast<const h4*>(&sXh[p][sample][4 * fg]);
            r0 = D0[0] + ob4.x + (float)xh4.x;
            r1 = D0[1] + ob4.y + (float)xh4.y;
            r2_= D0[2] + ob4.z + (float)xh4.z;
            r3 = D0[3] + ob4.w + (float)xh4.w;
        }
        // LN1 across e
        float s = (r0 + r1) + (r2_ + r3);
        s += __shfl_xor(s, 16); s += __shfl_xor(s, 32);
        float mu = s * (1.0f / 12.0f);
        float d0 = r0 - mu, d1 = r1 - mu, d2 = r2_ - mu, d3 = r3 - mu;
        float vv = e_ok ? ((d0*d0 + d1*d1) + (d2*d2 + d3*d3)) : 0.f;
        vv += __shfl_xor(vv, 16); vv += __shfl_xor(vv, 32);
        float rs = rsq_(vv * (1.0f / 12.0f) + 1e-5f);
        float y0 = 0.f, y1 = 0.f, y2 = 0.f, y3 = 0.f;
        if (e_ok) {
            y0 = d0 * rs * g1v.x + be1v.x;
            y1 = d1 * rs * g1v.y + be1v.y;
            y2 = d2 * rs * g1v.z + be1v.z;
            y3 = d3 * rs * g1v.w + be1v.w;
        }
        // GEMM1: H1^T = W1 . Y
        h4 yB = mkh4(pk16(y0, y1), pk16(y2, y3));
        f4v D1a = mfma16(W1f[0], yB, FZ);
        f4v D1b = mfma16(W1f[1], yB, FZ);
        h4 B1a = mkh4(pk16(tanh_(D1a[0] + b1t0.x), tanh_(D1a[1] + b1t0.y)),
                      pk16(tanh_(D1a[2] + b1t0.z), tanh_(D1a[3] + b1t0.w)));
        h4 B1b = mkh4(pk16(tanh_(D1b[0] + b1t1.x), tanh_(D1b[1] + b1t1.y)),
                      pk16(tanh_(D1b[2] + b1t1.z), tanh_(D1b[3] + b1t1.w)));
        // GEMM2: H2^T = W2 . TH1 (k=32 -> 2 steps)
        f4v D2a = mfma16(W2f[0][1], B1b, mfma16(W2f[0][0], B1a, FZ));
        f4v D2b = mfma16(W2f[1][1], B1b, mfma16(W2f[1][0], B1a, FZ));
        h4 B2a = mkh4(pk16(tanh_(D2a[0] + b2t0.x), tanh_(D2a[1] + b2t0.y)),
                      pk16(tanh_(D2a[2] + b2t0.z), tanh_(D2a[3] + b2t0.w)));
        h4 B2b = mkh4(pk16(tanh_(D2b[0] + b2t1.x), tanh_(D2b[1] + b2t1.y)),
                      pk16(tanh_(D2b[2] + b2t1.z), tanh_(D2b[3] + b2t1.w)));
        // GEMM3: FF^T = W3 . TH2
        f4v D3 = mfma16(W3f[1], B2b, mfma16(W3f[0], B2a, FZ));
        float q0 = 0.f, q1 = 0.f, q2 = 0.f, q3 = 0.f;
        if (e_ok) {
            q0 = y0 + tanh_(D3[0] + b3v.x);
            q1 = y1 + tanh_(D3[1] + b3v.y);
            q2 = y2 + tanh_(D3[2] + b3v.z);
            q3 = y3 + tanh_(D3[3] + b3v.w);
        }
        // LN2
        float s2 = (q0 + q1) + (q2 + q3);
        s2 += __shfl_xor(s2, 16); s2 += __shfl_xor(s2, 32);
        float mu2 = s2 * (1.0f / 12.0f);
        float e0 = q0 - mu2, e1 = q1 - mu2, e2 = q2 - mu2, e3 = q3 - mu2;
        float vv2 = e_ok ? ((e0*e0 + e1*e1) + (e2*e2 + e3*e3)) : 0.f;
        vv2 += __shfl_xor(vv2, 16); vv2 += __shfl_xor(vv2, 32);
        float rs2 = rsq_(vv2 * (1.0f / 12.0f) + 1e-5f);
        if (e_ok) {
            float z0 = e0 * rs2 * g2v.x + be2v.x;
            float z1 = e1 * rs2 * g2v.y + be2v.y;
            float z2 = e2 * rs2 * g2v.z + be2v.z;
            float z3 = e3 * rs2 * g2v.w + be2v.w;
            float* op = out + ((size_t)sample * NDIM + n) * EDIM + 4 * fg;
            *reinterpret_cast<float4*>(op) = make_float4(z0, z1, z2, z3);
        }
    }
}

extern "C" void kernel_launch(void* const* d_in, const int* in_sizes, int n_in,
                              void* d_out, int out_size, void* d_ws, size_t ws_size,
                              hipStream_t stream) {
    const float* x   = (const float*)d_in[0];
    const float* inw = (const float*)d_in[1];
    const float* inb = (const float*)d_in[2];
    const float* ow  = (const float*)d_in[3];
    const float* ob  = (const float*)d_in[4];
    const float* w1  = (const float*)d_in[5];
    const float* b1  = (const float*)d_in[6];
    const float* w2  = (const float*)d_in[7];
    const float* b2  = (const float*)d_in[8];
    const float* w3  = (const float*)d_in[9];
    const float* b3  = (const float*)d_in[10];
    const float* g1  = (const float*)d_in[11];
    const float* be1 = (const float*)d_in[12];
    const float* g2  = (const float*)d_in[13];
    const float* be2 = (const float*)d_in[14];
    float* out = (float*)d_out;

    encoder_fused<<<dim3(NDIM / 2), dim3(512), 0, stream>>>(
        x, inw, inb, ow, ob, w1, b1, w2, b2, w3, b3, g1, be1, g2, be2, out);
}

// Round 20
// 37.723 us; speedup vs baseline: 1.2704x; 1.2704x over previous
//
#include <hip/hip_runtime.h>

#define NDIM 4096
#define LDIM 128
#define EDIM 12
#define HDIM 32
#define XPITCH 16   // u16 pitch for staged x rows (12 used + 4 pad; 32B rows)

typedef float    f2  __attribute__((ext_vector_type(2)));
typedef float    f4v __attribute__((ext_vector_type(4)));
typedef _Float16 h2  __attribute__((ext_vector_type(2)));
typedef _Float16 h4  __attribute__((ext_vector_type(4)));

#ifndef __has_builtin
#define __has_builtin(x) 0
#endif

__device__ __forceinline__ float ex2_(float v) {
#if __has_builtin(__builtin_amdgcn_exp2f)
    return __builtin_amdgcn_exp2f(v);
#else
    return exp2f(v);
#endif
}
__device__ __forceinline__ float rcp_(float v) {
#if __has_builtin(__builtin_amdgcn_rcpf)
    return __builtin_amdgcn_rcpf(v);
#else
    return 1.0f / v;
#endif
}
__device__ __forceinline__ float rsq_(float v) {
#if __has_builtin(__builtin_amdgcn_rsqf)
    return __builtin_amdgcn_rsqf(v);
#else
    return rsqrtf(v);
#endif
}

__device__ __forceinline__ f2 mkf2(float a, float b) { f2 r; r.x = a; r.y = b; return r; }
__device__ __forceinline__ f2 pf(f2 a, f2 b, f2 c) { return __builtin_elementwise_fma(a, b, c); }
// packed tanh pair: tanh(v) = 1 - 2/(e^{2v}+1)
__device__ __forceinline__ f2 tanh2_(f2 v) {
    f2 vm = v * 2.8853900817779268f;
    f2 e; e.x = ex2_(vm.x); e.y = ex2_(vm.y);
    f2 ep = e + 1.0f;
    f2 rc; rc.x = rcp_(ep.x); rc.y = rcp_(ep.y);
    return pf(mkf2(-2.f, -2.f), rc, mkf2(1.f, 1.f));
}

__device__ __forceinline__ h2 pk16(float a, float b) {
#if __has_builtin(__builtin_amdgcn_cvt_pkrtz)
    return __builtin_bit_cast(h2, __builtin_amdgcn_cvt_pkrtz(a, b));
#else
    h2 r; r.x = (_Float16)a; r.y = (_Float16)b; return r;
#endif
}
__device__ __forceinline__ unsigned int h2u(h2 a) { return __builtin_bit_cast(unsigned int, a); }
__device__ __forceinline__ h4 mkh4(h2 a, h2 b) {
    h4 r; r.x = a.x; r.y = a.y; r.z = b.x; r.w = b.y; return r;
}
__device__ __forceinline__ h4 cvt_h4(float4 w) { return mkh4(pk16(w.x, w.y), pk16(w.z, w.w)); }
__device__ __forceinline__ h4 h4z() {
    h4 r; r.x = (_Float16)0; r.y = (_Float16)0; r.z = (_Float16)0; r.w = (_Float16)0; return r;
}

__device__ __forceinline__ f4v mfma16(h4 a, h4 b, f4v c) {
    return __builtin_amdgcn_mfma_f32_16x16x16f16(a, b, c, 0, 0, 0);
}

__global__ __launch_bounds__(256, 3)
void encoder_fused(const float* __restrict__ x,
                   const float* __restrict__ inw, const float* __restrict__ inb,
                   const float* __restrict__ ow,  const float* __restrict__ ob,
                   const float* __restrict__ w1,  const float* __restrict__ b1,
                   const float* __restrict__ w2,  const float* __restrict__ b2,
                   const float* __restrict__ w3,  const float* __restrict__ b3,
                   const float* __restrict__ g1,  const float* __restrict__ be1,
                   const float* __restrict__ g2,  const float* __restrict__ be2,
                   float* __restrict__ out)
{
    const int tid  = threadIdx.x;
    const int p    = tid >> 7;         // n within block (0..1)
    const int l    = tid & 127;        // row staged by this thread
    const int wv2  = (tid >> 6) & 1;   // wave within the n; owns samples 64*wv2..+63
    const int lane = tid & 63;
    const int fr   = lane & 15;        // fragment row/col slot
    const int fg   = lane >> 4;        // fragment k-group (0..3)
    const int n    = blockIdx.x * 2 + p;
    const bool e_ok = (fg < 3);        // feat 4*fg+j < 12

    __shared__ unsigned short sXh[2][LDIM][XPITCH];  // x rows f16 (8.2 KB)
    __shared__ unsigned short sVT[2][13][132];       // V^T f16 + ones row (6.9 KB)
    __shared__ h4             sKf[2][8][64];         // K A-frags (8.2 KB)

    const float SCALE = 0.2886751345948129f;   // 1/sqrt(12)
    const float L2E   = 1.4426950408889634f;
    const float SL2E  = SCALE * L2E;
    const f4v   FZ    = (f4v){0.f, 0.f, 0.f, 0.f};

    // ====== stage x row l as f16 (wave-local rows -> no barrier needed) ====
    {
        const float* xp = x + ((size_t)l * NDIM + n) * EDIM;
        float4 xa = *reinterpret_cast<const float4*>(xp);
        float4 xb = *reinterpret_cast<const float4*>(xp + 4);
        float4 xc = *reinterpret_cast<const float4*>(xp + 8);
        unsigned int u0 = h2u(pk16(xa.x, xa.y)), u1 = h2u(pk16(xa.z, xa.w));
        unsigned int u2 = h2u(pk16(xb.x, xb.y)), u3 = h2u(pk16(xb.z, xb.w));
        unsigned int u4 = h2u(pk16(xc.x, xc.y)), u5 = h2u(pk16(xc.z, xc.w));
        *reinterpret_cast<uint4*>(&sXh[p][l][0]) = make_uint4(u0, u1, u2, u3);
        *reinterpret_cast<uint4*>(&sXh[p][l][8]) = make_uint4(u4, u5, 0u, 0u);
        // ones row for the psum-via-MFMA trick (cross-wave read; barrier below)
        sVT[p][12][l] = (unsigned short)0x3C00;   // f16 1.0
    }

    // ---- projection weight A-frags (rows fr = fout, k = feat 4fg+j) ----
    h4 WQp = h4z(), WKp = h4z(), WVp = h4z();
    if (fr < 12 && e_ok) {
        WQp = cvt_h4(*reinterpret_cast<const float4*>(inw + (     fr) * 12 + 4 * fg));
        WKp = cvt_h4(*reinterpret_cast<const float4*>(inw + (12 + fr) * 12 + 4 * fg));
        WVp = cvt_h4(*reinterpret_cast<const float4*>(inw + (24 + fr) * 12 + 4 * fg));
    }
    const float4 F4Z = make_float4(0.f, 0.f, 0.f, 0.f);
    float4 bq4 = e_ok ? *reinterpret_cast<const float4*>(inb +      4 * fg) : F4Z;
    float4 bk4 = e_ok ? *reinterpret_cast<const float4*>(inb + 12 + 4 * fg) : F4Z;
    float4 bv4 = e_ok ? *reinterpret_cast<const float4*>(inb + 24 + 4 * fg) : F4Z;
    // fold SCALE*L2E into the Q bias (softmax shift deleted: per-query uniform
    // scaling of p cancels between O and the ones-row denominator)
    float4 bq4s = make_float4(bq4.x * SL2E, bq4.y * SL2E, bq4.z * SL2E, bq4.w * SL2E);

    // NOTE: no barrier here — each wave's phase-1 reads only its own staged
    // rows of sXh (in-wave LDS RAW is ordered); cross-wave data (sKf, sVT
    // incl. ones row) is guarded by the barrier after phase 1.

    // ================= phase 1: QKV projection via MFMA ====================
    h4 qf[4];
    h4 xres[4];   // register-carried residual frag (== phase-3 sample frag)
    #pragma unroll
    for (int st = 0; st < 4; ++st) {
        const int srow = 64 * wv2 + 16 * st;   // base sample/key of this tile
        h4 xB = *reinterpret_cast<const h4*>(&sXh[p][srow + fr][4 * fg]);
        xres[st] = xB;

        // Q: C-layout == B-frag for QK^T; q * SCALE * L2E in one fma each
        f4v Dq = mfma16(WQp, xB, FZ);
        qf[st] = mkh4(pk16(fmaf(Dq[0], SL2E, bq4s.x), fmaf(Dq[1], SL2E, bq4s.y)),
                      pk16(fmaf(Dq[2], SL2E, bq4s.z), fmaf(Dq[3], SL2E, bq4s.w)));

        // K: C-layout == A-frag for S^T; park in LDS for cross-wave reads
        f4v Dk = mfma16(WKp, xB, FZ);
        sKf[p][4 * wv2 + st][lane] = mkh4(pk16(Dk[0] + bk4.x, Dk[1] + bk4.y),
                                          pk16(Dk[2] + bk4.z, Dk[3] + bk4.w));

        // V: transpose into sVT[feat][key] for the PV A-frag
        f4v Dv = mfma16(WVp, xB, FZ);
        if (e_ok) {
            sVT[p][4*fg + 0][srow + fr] = __builtin_bit_cast(unsigned short, (_Float16)(Dv[0] + bv4.x));
            sVT[p][4*fg + 1][srow + fr] = __builtin_bit_cast(unsigned short, (_Float16)(Dv[1] + bv4.y));
            sVT[p][4*fg + 2][srow + fr] = __builtin_bit_cast(unsigned short, (_Float16)(Dv[2] + bv4.z));
            sVT[p][4*fg + 3][srow + fr] = __builtin_bit_cast(unsigned short, (_Float16)(Dv[3] + bv4.w));
        }
    }
    __syncthreads();   // sKf / sVT (incl. ones row) complete

    // ================= phase 2: attention via MFMA (no softmax shift) ======
    f4v oc[4];
    #pragma unroll
    for (int st = 0; st < 4; ++st) oc[st] = FZ;

    #pragma unroll
    for (int u = 0; u < 8; ++u) {
        h4 kf = sKf[p][u][lane];
        h4 vf = h4z();
        if (fr <= 12)   // rows 0..11 = V features, row 12 = ones (psum row)
            vf = *reinterpret_cast<const h4*>(&sVT[p][fr][16 * u + 4 * fg]);
        #pragma unroll
        for (int st = 0; st < 4; ++st) {
            f4v c = mfma16(kf, qf[st], FZ);    // S^T[key][query] * log2(e)
            float p0 = ex2_(c[0]);
            float p1 = ex2_(c[1]);
            float p2 = ex2_(c[2]);
            float p3 = ex2_(c[3]);
            h4 paf = mkh4(pk16(p0, p1), pk16(p2, p3));
            oc[st] = mfma16(vf, paf, oc[st]);  // O^T[feat][sample]; row12 = psum
        }
    }
    float inv[4];
    #pragma unroll
    for (int st = 0; st < 4; ++st) {
        float ps = __shfl(oc[st][0], fr + 48);   // row 12 lives at (fr, fg=3), j=0
        inv[st] = rcp_(fmaxf(ps, 1e-35f));
    }

    // ============ epilogue constants: weight A-frags (f16) + biases ========
    h4 OWf = h4z();
    if (fr < 12 && e_ok)
        OWf = cvt_h4(*reinterpret_cast<const float4*>(ow + fr * 12 + 4 * fg));
    h4 W1f[2] = {h4z(), h4z()};
    if (e_ok) {
        W1f[0] = cvt_h4(*reinterpret_cast<const float4*>(w1 + (fr     ) * 12 + 4 * fg));
        W1f[1] = cvt_h4(*reinterpret_cast<const float4*>(w1 + (fr + 16) * 12 + 4 * fg));
    }
    h4 W2f[2][2];
    #pragma unroll
    for (int gt = 0; gt < 2; ++gt)
        #pragma unroll
        for (int ks = 0; ks < 2; ++ks)
            W2f[gt][ks] = cvt_h4(*reinterpret_cast<const float4*>(
                w2 + (16*gt + fr) * 32 + 16*ks + 4*fg));
    h4 W3f[2] = {h4z(), h4z()};
    if (fr < 12) {
        W3f[0] = cvt_h4(*reinterpret_cast<const float4*>(w3 + fr * 32 +      4 * fg));
        W3f[1] = cvt_h4(*reinterpret_cast<const float4*>(w3 + fr * 32 + 16 + 4 * fg));
    }
    float4 ob4  = e_ok ? *reinterpret_cast<const float4*>(ob  + 4*fg) : F4Z;
    float4 b3v  = e_ok ? *reinterpret_cast<const float4*>(b3  + 4*fg) : F4Z;
    float4 g1v  = e_ok ? *reinterpret_cast<const float4*>(g1  + 4*fg) : F4Z;
    float4 be1v = e_ok ? *reinterpret_cast<const float4*>(be1 + 4*fg) : F4Z;
    float4 g2v  = e_ok ? *reinterpret_cast<const float4*>(g2  + 4*fg) : F4Z;
    float4 be2v = e_ok ? *reinterpret_cast<const float4*>(be2 + 4*fg) : F4Z;
    float4 b1t0 = *reinterpret_cast<const float4*>(b1 +      4*fg);
    float4 b1t1 = *reinterpret_cast<const float4*>(b1 + 16 + 4*fg);
    float4 b2t0 = *reinterpret_cast<const float4*>(b2 +      4*fg);
    float4 b2t1 = *reinterpret_cast<const float4*>(b2 + 16 + 4*fg);
    // f2 views of the per-lane bias/affine constants
    f2 obA  = mkf2(ob4.x,  ob4.y),  obB  = mkf2(ob4.z,  ob4.w);
    f2 g1A  = mkf2(g1v.x,  g1v.y),  g1B  = mkf2(g1v.z,  g1v.w);
    f2 be1A = mkf2(be1v.x, be1v.y), be1B = mkf2(be1v.z, be1v.w);
    f2 g2A  = mkf2(g2v.x,  g2v.y),  g2B  = mkf2(g2v.z,  g2v.w);
    f2 be2A = mkf2(be2v.x, be2v.y), be2B = mkf2(be2v.z, be2v.w);
    f2 b3A  = mkf2(b3v.x,  b3v.y),  b3B  = mkf2(b3v.z,  b3v.w);
    f2 b10A = mkf2(b1t0.x, b1t0.y), b10B = mkf2(b1t0.z, b1t0.w);
    f2 b11A = mkf2(b1t1.x, b1t1.y), b11B = mkf2(b1t1.z, b1t1.w);
    f2 b20A = mkf2(b2t0.x, b2t0.y), b20B = mkf2(b2t0.z, b2t0.w);
    f2 b21A = mkf2(b2t1.x, b2t1.y), b21B = mkf2(b2t1.z, b2t1.w);

    // ================= phase 3: fused MFMA epilogue (packed f32) ===========
    #pragma unroll
    for (int st = 0; st < 4; ++st) {
        const int sample = 64*wv2 + 16*st + fr;
        // normalized O^T as B-frag (f16)
        f2 oA = mkf2(oc[st][0], oc[st][1]) * inv[st];
        f2 oB = mkf2(oc[st][2], oc[st][3]) * inv[st];
        h4 B0 = mkh4(pk16(oA.x, oA.y), pk16(oB.x, oB.y));
        // out-proj: D0 = OW . O -> AttnProj^T[fout][sample]
        f4v D0 = mfma16(OWf, B0, FZ);
        // residual from register-carried x frag (zeros on pad lanes)
        f2 xA = mkf2((float)xres[st].x, (float)xres[st].y);
        f2 xB_ = mkf2((float)xres[st].z, (float)xres[st].w);
        f2 rA = (mkf2(D0[0], D0[1]) + obA) + xA;
        f2 rB = (mkf2(D0[2], D0[3]) + obB) + xB_;
        // LN1 across e
        f2 ts = rA + rB;
        float s = ts.x + ts.y;
        s += __shfl_xor(s, 16); s += __shfl_xor(s, 32);
        float mu = s * (1.0f / 12.0f);
        f2 muv = mkf2(mu, mu);
        f2 dA = rA - muv, dB = rB - muv;
        f2 vsv = dA * dA; vsv = pf(dB, dB, vsv);
        float vv = e_ok ? (vsv.x + vsv.y) : 0.f;
        vv += __shfl_xor(vv, 16); vv += __shfl_xor(vv, 32);
        float rs = rsq_(vv * (1.0f / 12.0f) + 1e-5f);
        f2 rsv = mkf2(rs, rs);
        f2 yA = pf(dA * rsv, g1A, be1A);
        f2 yB_ = pf(dB * rsv, g1B, be1B);
        // GEMM1: H1^T = W1 . Y
        h4 yF = mkh4(pk16(yA.x, yA.y), pk16(yB_.x, yB_.y));
        f4v D1a = mfma16(W1f[0], yF, FZ);
        f4v D1b = mfma16(W1f[1], yF, FZ);
        f2 t0 = tanh2_(mkf2(D1a[0], D1a[1]) + b10A);
        f2 t1 = tanh2_(mkf2(D1a[2], D1a[3]) + b10B);
        f2 t2 = tanh2_(mkf2(D1b[0], D1b[1]) + b11A);
        f2 t3 = tanh2_(mkf2(D1b[2], D1b[3]) + b11B);
        h4 B1a = mkh4(pk16(t0.x, t0.y), pk16(t1.x, t1.y));
        h4 B1b = mkh4(pk16(t2.x, t2.y), pk16(t3.x, t3.y));
        // GEMM2: H2^T = W2 . TH1 (k=32 -> 2 steps)
        f4v D2a = mfma16(W2f[0][1], B1b, mfma16(W2f[0][0], B1a, FZ));
        f4v D2b = mfma16(W2f[1][1], B1b, mfma16(W2f[1][0], B1a, FZ));
        f2 u0 = tanh2_(mkf2(D2a[0], D2a[1]) + b20A);
        f2 u1 = tanh2_(mkf2(D2a[2], D2a[3]) + b20B);
        f2 u2 = tanh2_(mkf2(D2b[0], D2b[1]) + b21A);
        f2 u3 = tanh2_(mkf2(D2b[2], D2b[3]) + b21B);
        h4 B2a = mkh4(pk16(u0.x, u0.y), pk16(u1.x, u1.y));
        h4 B2b = mkh4(pk16(u2.x, u2.y), pk16(u3.x, u3.y));
        // GEMM3: FF^T = W3 . TH2
        f4v D3 = mfma16(W3f[1], B2b, mfma16(W3f[0], B2a, FZ));
        f2 qA = yA + tanh2_(mkf2(D3[0], D3[1]) + b3A);
        f2 qB = yB_ + tanh2_(mkf2(D3[2], D3[3]) + b3B);
        // LN2
        f2 ts2 = qA + qB;
        float s2 = ts2.x + ts2.y;
        s2 += __shfl_xor(s2, 16); s2 += __shfl_xor(s2, 32);
        float mu2 = s2 * (1.0f / 12.0f);
        f2 mu2v = mkf2(mu2, mu2);
        f2 eA = qA - mu2v, eB = qB - mu2v;
        f2 vs2v = eA * eA; vs2v = pf(eB, eB, vs2v);
        float vv2 = e_ok ? (vs2v.x + vs2v.y) : 0.f;
        vv2 += __shfl_xor(vv2, 16); vv2 += __shfl_xor(vv2, 32);
        float rs2 = rsq_(vv2 * (1.0f / 12.0f) + 1e-5f);
        f2 rs2v = mkf2(rs2, rs2);
        if (e_ok) {
            f2 zA = pf(eA * rs2v, g2A, be2A);
            f2 zB = pf(eB * rs2v, g2B, be2B);
            float* op = out + ((size_t)sample * NDIM + n) * EDIM + 4 * fg;
            *reinterpret_cast<float4*>(op) = make_float4(zA.x, zA.y, zB.x, zB.y);
        }
    }
}

extern "C" void kernel_launch(void* const* d_in, const int* in_sizes, int n_in,
                              void* d_out, int out_size, void* d_ws, size_t ws_size,
                              hipStream_t stream) {
    const float* x   = (const float*)d_in[0];
    const float* inw = (const float*)d_in[1];
    const float* inb = (const float*)d_in[2];
    const float* ow  = (const float*)d_in[3];
    const float* ob  = (const float*)d_in[4];
    const float* w1  = (const float*)d_in[5];
    const float* b1  = (const float*)d_in[6];
    const float* w2  = (const float*)d_in[7];
    const float* b2  = (const float*)d_in[8];
    const float* w3  = (const float*)d_in[9];
    const float* b3  = (const float*)d_in[10];
    const float* g1  = (const float*)d_in[11];
    const float* be1 = (const float*)d_in[12];
    const float* g2  = (const float*)d_in[13];
    const float* be2 = (const float*)d_in[14];
    float* out = (float*)d_out;

    encoder_fused<<<dim3(NDIM / 2), dim3(256), 0, stream>>>(
        x, inw, inb, ow, ob, w1, b1, w2, b2, w3, b3, g1, be1, g2, be2, out);
}